// Round 5
// baseline (273.033 us; speedup 1.0000x reference)
//
#include <hip/hip_runtime.h>

typedef unsigned short u16;
typedef unsigned char u8;
typedef unsigned int u32;

using s16x8 = __attribute__((ext_vector_type(8))) short;
using u16x4 = __attribute__((ext_vector_type(4))) u16;
using f32x4 = __attribute__((ext_vector_type(4))) float;

constexpr int N_ = 3072;
constexpr int E_ = 512;
constexpr int H_ = 8;

__device__ __forceinline__ u16 f2bf(float f) {
    u32 u = __float_as_uint(f);
    u += 0x7fffu + ((u >> 16) & 1u);
    return (u16)(u >> 16);
}
__device__ __forceinline__ float b2f(u16 u) {
    return __uint_as_float(((u32)u) << 16);
}

// ---------- K0: f32 -> bf16 convert, 4 elems/thread ----------
__global__ void k_cvt(const float* __restrict__ src, u16* __restrict__ dst, int n4) {
    int i = blockIdx.x * blockDim.x + threadIdx.x;
    if (i >= n4) return;
    float4 v = ((const float4*)src)[i];
    u16x4 o = { f2bf(v.x), f2bf(v.y), f2bf(v.z), f2bf(v.w) };
    ((u16x4*)dst)[i] = o;
}

// ---------- K1: projection GEMM  C[3072][512] = A[3072][512] * W[512][512]^T (bf16 out)
__global__ __launch_bounds__(256) void k_proj(
    const u16* __restrict__ xb, const u16* __restrict__ wqb,
    const u16* __restrict__ wkb, u16* __restrict__ Qb, u16* __restrict__ Kb)
{
    const int t = threadIdx.x, lane = t & 63, w = t >> 6;
    const int lr = lane & 15, lg = lane >> 4;
    const int n0 = blockIdx.x * 64 + w * 16;
    const int e0 = blockIdx.y * 64;
    const u16* wb = blockIdx.z ? wkb : wqb;
    u16* dst = blockIdx.z ? Kb : Qb;

    f32x4 acc[4];
#pragma unroll
    for (int cb = 0; cb < 4; ++cb) acc[cb] = f32x4{0.f, 0.f, 0.f, 0.f};

    for (int k0 = 0; k0 < 512; k0 += 32) {
        s16x8 a = *(const s16x8*)(xb + (n0 + lr) * 512 + k0 + lg * 8);
#pragma unroll
        for (int cb = 0; cb < 4; ++cb) {
            s16x8 b = *(const s16x8*)(wb + (e0 + cb * 16 + lr) * 512 + k0 + lg * 8);
            acc[cb] = __builtin_amdgcn_mfma_f32_16x16x32_bf16(a, b, acc[cb], 0, 0, 0);
        }
    }
#pragma unroll
    for (int cb = 0; cb < 4; ++cb)
#pragma unroll
        for (int r = 0; r < 4; ++r)
            dst[(n0 + lg * 4 + r) * 512 + e0 + cb * 16 + lr] = f2bf(acc[cb][r]);
}

// ---------- K2t: transpose Kb[3072][512] -> Kt[512][3072] ----------
__global__ __launch_bounds__(256) void k_transpose(const u16* __restrict__ Kb,
                                                   u16* __restrict__ Kt) {
    __shared__ u16 tile[64 * 68];
    const int t = threadIdx.x;
    const int n0 = blockIdx.x * 64, e0 = blockIdx.y * 64;
    const int tr = t >> 4, c4 = (t & 15) * 4;
#pragma unroll
    for (int p = 0; p < 4; ++p) {
        int row = p * 16 + tr;
        u16x4 v = *(const u16x4*)(Kb + (n0 + row) * 512 + e0 + c4);
        *(u16x4*)&tile[row * 68 + c4] = v;
    }
    __syncthreads();
#pragma unroll
    for (int p = 0; p < 4; ++p) {
        int er = p * 16 + tr;
        u16x4 v = { tile[(c4 + 0) * 68 + er], tile[(c4 + 1) * 68 + er],
                    tile[(c4 + 2) * 68 + er], tile[(c4 + 3) * 68 + er] };
        *(u16x4*)(Kt + (e0 + er) * 3072 + n0 + c4) = v;
    }
}

// ---------- K3: pass 1 — partial sumexp over one m-chunk (adj is INT32) ----------
__global__ __launch_bounds__(256) void k_pass1(
    const u16* __restrict__ Qb, const u16* __restrict__ Kb,
    const int* __restrict__ adj, float* __restrict__ sep)
{
    const int t = threadIdx.x, lane = t & 63, w = t >> 6;
    const int lr = lane & 15, lg = lane >> 4;
    const int n0 = blockIdx.x * 64 + w * 16;
    const int mbase = blockIdx.y * 384;

    s16x8 qa[8][2];
#pragma unroll
    for (int h = 0; h < 8; ++h)
#pragma unroll
        for (int ks = 0; ks < 2; ++ks)
            qa[h][ks] = *(const s16x8*)(Qb + (n0 + lr) * 512 + h * 64 + ks * 32 + lg * 8);

    float racc[8][4];
#pragma unroll
    for (int h = 0; h < 8; ++h)
#pragma unroll
        for (int r = 0; r < 4; ++r) racc[h][r] = 0.f;

    for (int ms = 0; ms < 12; ++ms) {
        const int m0 = mbase + ms * 32;
        int adjv[2][4];
#pragma unroll
        for (int cb = 0; cb < 2; ++cb)
#pragma unroll
            for (int r = 0; r < 4; ++r)
                adjv[cb][r] = adj[(n0 + lg * 4 + r) * 3072 + m0 + cb * 16 + lr];
#pragma unroll
        for (int h = 0; h < 8; ++h) {
            s16x8 b00 = *(const s16x8*)(Kb + (m0 + lr) * 512 + h * 64 + lg * 8);
            s16x8 b01 = *(const s16x8*)(Kb + (m0 + lr) * 512 + h * 64 + 32 + lg * 8);
            s16x8 b10 = *(const s16x8*)(Kb + (m0 + 16 + lr) * 512 + h * 64 + lg * 8);
            s16x8 b11 = *(const s16x8*)(Kb + (m0 + 16 + lr) * 512 + h * 64 + 32 + lg * 8);
            f32x4 z = {0.f, 0.f, 0.f, 0.f};
            f32x4 s0 = __builtin_amdgcn_mfma_f32_16x16x32_bf16(qa[h][0], b00, z, 0, 0, 0);
            s0 = __builtin_amdgcn_mfma_f32_16x16x32_bf16(qa[h][1], b01, s0, 0, 0, 0);
            f32x4 s1 = __builtin_amdgcn_mfma_f32_16x16x32_bf16(qa[h][0], b10, z, 0, 0, 0);
            s1 = __builtin_amdgcn_mfma_f32_16x16x32_bf16(qa[h][1], b11, s1, 0, 0, 0);
#pragma unroll
            for (int r = 0; r < 4; ++r) {
                float e0v = adjv[0][r] ? __expf(0.125f * s0[r]) : 0.f;
                float e1v = adjv[1][r] ? __expf(0.125f * s1[r]) : 0.f;
                racc[h][r] += e0v + e1v;
            }
        }
    }
#pragma unroll
    for (int h = 0; h < 8; ++h)
#pragma unroll
        for (int r = 0; r < 4; ++r) {
            float v = racc[h][r];
            v += __shfl_xor(v, 1); v += __shfl_xor(v, 2);
            v += __shfl_xor(v, 4); v += __shfl_xor(v, 8);
            if (lr == 0) sep[(blockIdx.y * 8 + h) * N_ + n0 + lg * 4 + r] = v;
        }
}

// ---------- K4: finish — inv_se + energies, per-lane scalar ----------
__global__ __launch_bounds__(64) void k_finish(
    const u16* __restrict__ Qb, const float* __restrict__ sep,
    float* __restrict__ inv_se, float* __restrict__ energies)
{
    const int lane = threadIdx.x;
    const int r = lane >> 3;
    const int h = lane & 7;
    const int n = blockIdx.x * 8 + r;

    float se = 0.f;
#pragma unroll
    for (int c = 0; c < 8; ++c) se += sep[(c * 8 + h) * N_ + n];

    float q2 = 0.f;
    const u16* qrow = Qb + n * 512 + h * 64;
#pragma unroll
    for (int j = 0; j < 8; ++j) {
        s16x8 v = *(const s16x8*)(qrow + j * 8);
#pragma unroll
        for (int e = 0; e < 8; ++e) {
            float f = b2f((u16)v[e]);
            q2 += f * f;
        }
    }

    inv_se[h * N_ + n] = 1.f / se;
    energies[h * N_ + n] = -8.0f * logf(se) + 0.5f * q2;
}

// ---------- K5: pass 2 — attn_mean + partial out over one m-chunk (adj INT32) ----------
__global__ __launch_bounds__(256, 2) void k_pass2(
    const u16* __restrict__ Qb, const u16* __restrict__ Kb,
    const u16* __restrict__ Kt, const float* __restrict__ inv_se,
    const int* __restrict__ adj, float* __restrict__ amean,
    float* __restrict__ pout, int mrange)
{
    __shared__ u16 Plds[8 * 32 * 40];   // [head][n 32][m 32 pad->40] bf16
    const int t = threadIdx.x, lane = t & 63, w = t >> 6;
    const int lr = lane & 15, lg = lane >> 4;
    const int n0 = blockIdx.x * 32;
    const int mbase = blockIdx.y * mrange;
    const int h0 = w * 2;

    s16x8 qa[2][2][2];   // [hh][rb][ks]
#pragma unroll
    for (int hh = 0; hh < 2; ++hh)
#pragma unroll
        for (int rb = 0; rb < 2; ++rb)
#pragma unroll
            for (int ks = 0; ks < 2; ++ks)
                qa[hh][rb][ks] = *(const s16x8*)(Qb + (n0 + rb * 16 + lr) * 512 +
                                                 (h0 + hh) * 64 + ks * 32 + lg * 8);
    f32x4 invv[2][2];
#pragma unroll
    for (int hh = 0; hh < 2; ++hh)
#pragma unroll
        for (int rb = 0; rb < 2; ++rb)
            invv[hh][rb] = *(const f32x4*)(inv_se + (h0 + hh) * N_ + n0 + rb * 16 + lg * 4);

    f32x4 oacc[2][2][4];  // [hh][rb][db]
#pragma unroll
    for (int hh = 0; hh < 2; ++hh)
#pragma unroll
        for (int rb = 0; rb < 2; ++rb)
#pragma unroll
            for (int db = 0; db < 4; ++db) oacc[hh][rb][db] = f32x4{0.f, 0.f, 0.f, 0.f};

    const int msteps = mrange >> 5;
    for (int ms = 0; ms < msteps; ++ms) {
        const int m0 = mbase + ms * 32;
        int adjv[2][2][4];   // [rb][cb][r]
#pragma unroll
        for (int rb = 0; rb < 2; ++rb)
#pragma unroll
            for (int cb = 0; cb < 2; ++cb)
#pragma unroll
                for (int r = 0; r < 4; ++r)
                    adjv[rb][cb][r] = adj[(n0 + rb * 16 + lg * 4 + r) * 3072 +
                                          m0 + cb * 16 + lr];
#pragma unroll
        for (int hh = 0; hh < 2; ++hh) {
            const int h = h0 + hh;
            s16x8 b[2][2];
#pragma unroll
            for (int cb = 0; cb < 2; ++cb)
#pragma unroll
                for (int ks = 0; ks < 2; ++ks)
                    b[cb][ks] = *(const s16x8*)(Kb + (m0 + cb * 16 + lr) * 512 +
                                                h * 64 + ks * 32 + lg * 8);
            f32x4 z = {0.f, 0.f, 0.f, 0.f};
            f32x4 s[2][2];
#pragma unroll
            for (int rb = 0; rb < 2; ++rb)
#pragma unroll
                for (int cb = 0; cb < 2; ++cb) {
                    s[rb][cb] = __builtin_amdgcn_mfma_f32_16x16x32_bf16(qa[hh][rb][0], b[cb][0], z, 0, 0, 0);
                    s[rb][cb] = __builtin_amdgcn_mfma_f32_16x16x32_bf16(qa[hh][rb][1], b[cb][1], s[rb][cb], 0, 0, 0);
                }
#pragma unroll
            for (int rb = 0; rb < 2; ++rb)
#pragma unroll
                for (int cb = 0; cb < 2; ++cb)
#pragma unroll
                    for (int r = 0; r < 4; ++r) {
                        float p = adjv[rb][cb][r]
                                ? __expf(0.125f * s[rb][cb][r]) * invv[hh][rb][r] : 0.f;
                        Plds[(h * 32 + rb * 16 + lg * 4 + r) * 40 + cb * 16 + lr] = f2bf(p);
                    }
        }
        __syncthreads();
        {   // attn_mean: each thread 4 consecutive m of one row, summed over 8 heads
            const int nl = t >> 3;
            const int m4 = (t & 7) * 4;
            f32x4 sum = {0.f, 0.f, 0.f, 0.f};
#pragma unroll
            for (int h = 0; h < 8; ++h) {
                u16x4 pv = *(const u16x4*)&Plds[(h * 32 + nl) * 40 + m4];
#pragma unroll
                for (int j = 0; j < 4; ++j) sum[j] += b2f(pv[j]);
            }
            f32x4 o;
#pragma unroll
            for (int j = 0; j < 4; ++j) o[j] = sum[j] * 0.125f;
            *(f32x4*)(amean + (n0 + nl) * 3072 + m0 + m4) = o;
        }
        // PV for own heads
#pragma unroll
        for (int hh = 0; hh < 2; ++hh) {
            const int h = h0 + hh;
            s16x8 pa[2];
#pragma unroll
            for (int rb = 0; rb < 2; ++rb)
                pa[rb] = *(const s16x8*)&Plds[(h * 32 + rb * 16 + lr) * 40 + lg * 8];
            s16x8 kb4[4];
#pragma unroll
            for (int db = 0; db < 4; ++db)
                kb4[db] = *(const s16x8*)(Kt + (h * 64 + db * 16 + lr) * 3072 + m0 + lg * 8);
#pragma unroll
            for (int rb = 0; rb < 2; ++rb)
#pragma unroll
                for (int db = 0; db < 4; ++db)
                    oacc[hh][rb][db] = __builtin_amdgcn_mfma_f32_16x16x32_bf16(
                        pa[rb], kb4[db], oacc[hh][rb][db], 0, 0, 0);
        }
        __syncthreads();
    }
    float* po = pout + (size_t)blockIdx.y * (N_ * E_);
#pragma unroll
    for (int hh = 0; hh < 2; ++hh)
#pragma unroll
        for (int rb = 0; rb < 2; ++rb)
#pragma unroll
            for (int db = 0; db < 4; ++db)
#pragma unroll
                for (int r = 0; r < 4; ++r)
                    po[(n0 + rb * 16 + lg * 4 + r) * 512 +
                       (h0 + hh) * 64 + db * 16 + lr] = oacc[hh][rb][db][r];
}

// ---------- K6: reduce partial out ----------
__global__ void k_reduce(const float* __restrict__ pout, float* __restrict__ out, int c2) {
    int i = blockIdx.x * blockDim.x + threadIdx.x;
    if (i >= (N_ * E_) / 4) return;
    const f32x4* p4 = (const f32x4*)pout;
    f32x4 s = p4[i];
    for (int c = 1; c < c2; ++c) s += p4[c * ((N_ * E_) / 4) + i];
    ((f32x4*)out)[i] = s;
}

extern "C" void kernel_launch(void* const* d_in, const int* in_sizes, int n_in,
                              void* d_out, int out_size, void* d_ws, size_t ws_size,
                              hipStream_t stream) {
    const float* x  = (const float*)d_in[0];
    const int*  adj = (const int*)d_in[1];     // bool input arrives as int32
    const float* WQ = (const float*)d_in[2];
    const float* WK = (const float*)d_in[3];
    float* out      = (float*)d_out;
    float* amean    = out + (size_t)N_ * E_;
    float* energies = out + (size_t)N_ * E_ + (size_t)N_ * N_;

    char* ws = (char*)d_ws;
    u16* xb     = (u16*)(ws);
    u16* wqb    = (u16*)(ws + 3145728);
    u16* wkb    = (u16*)(ws + 3670016);
    u16* Qb     = (u16*)(ws + 4194304);
    u16* Kb     = (u16*)(ws + 7340032);
    u16* Kt     = (u16*)(ws + 10485760);
    float* sep  = (float*)(ws + 13729792);
    float* inv_se = (float*)(ws + 14516224);
    float* pout = (float*)(ws + 14614528);

    int c2 = 1;
    const int cands[5] = {6, 4, 3, 2, 1};
    for (int i = 0; i < 5; ++i) {
        if (14614528ull + (size_t)cands[i] * ((size_t)N_ * E_ * 4) <= ws_size) {
            c2 = cands[i];
            break;
        }
    }

    k_cvt<<<dim3(1536), dim3(256), 0, stream>>>(x, xb, (N_ * 512) / 4);
    k_cvt<<<dim3(256), dim3(256), 0, stream>>>(WQ, wqb, (512 * 512) / 4);
    k_cvt<<<dim3(256), dim3(256), 0, stream>>>(WK, wkb, (512 * 512) / 4);
    k_proj<<<dim3(48, 8, 2), dim3(256), 0, stream>>>(xb, wqb, wkb, Qb, Kb);
    k_transpose<<<dim3(48, 8), dim3(256), 0, stream>>>(Kb, Kt);
    k_pass1<<<dim3(48, 8), dim3(256), 0, stream>>>(Qb, Kb, adj, sep);
    k_finish<<<dim3(384), dim3(64), 0, stream>>>(Qb, sep, inv_se, energies);
    k_pass2<<<dim3(96, c2), dim3(256), 0, stream>>>(Qb, Kb, Kt, inv_se, adj, amean, pout,
                                                    N_ / c2);
    k_reduce<<<dim3(1536), dim3(256), 0, stream>>>(pout, out, c2);
}

// Round 6
// 247.116 us; speedup vs baseline: 1.1049x; 1.1049x over previous
//
#include <hip/hip_runtime.h>

typedef unsigned short u16;
typedef unsigned char u8;
typedef unsigned int u32;
typedef unsigned long long u64;

using s16x8 = __attribute__((ext_vector_type(8))) short;
using u16x4 = __attribute__((ext_vector_type(4))) u16;
using f32x4 = __attribute__((ext_vector_type(4))) float;

constexpr int N_ = 3072;
constexpr int E_ = 512;
constexpr int H_ = 8;
// exp(SCALING*s) = exp2(s * 0.125*log2(e))
#define EXPSC 0.1803368801111203f

__device__ __forceinline__ u16 f2bf(float f) {
    u32 u = __float_as_uint(f);
    u += 0x7fffu + ((u >> 16) & 1u);
    return (u16)(u >> 16);
}
__device__ __forceinline__ float b2f(u16 u) {
    return __uint_as_float(((u32)u) << 16);
}

// ---------- K0: f32 -> bf16 convert ----------
__global__ void k_cvt(const float* __restrict__ src, u16* __restrict__ dst, int n4) {
    int i = blockIdx.x * blockDim.x + threadIdx.x;
    if (i >= n4) return;
    float4 v = ((const float4*)src)[i];
    u16x4 o = { f2bf(v.x), f2bf(v.y), f2bf(v.z), f2bf(v.w) };
    ((u16x4*)dst)[i] = o;
}

// ---------- K0b: pack adj int32 -> bitmask u64 (64 cols/word, row-major) ----------
__global__ void k_adjpack(const int* __restrict__ adj, u64* __restrict__ adjp) {
    int i = blockIdx.x * blockDim.x + threadIdx.x;
    int v = adj[i];
    u64 m = __ballot(v != 0);
    if ((threadIdx.x & 63) == 0) adjp[i >> 6] = m;
}

// ---------- K1: projection GEMM (unchanged, proven) ----------
__global__ __launch_bounds__(256) void k_proj(
    const u16* __restrict__ xb, const u16* __restrict__ wqb,
    const u16* __restrict__ wkb, u16* __restrict__ Qb, u16* __restrict__ Kb)
{
    const int t = threadIdx.x, lane = t & 63, w = t >> 6;
    const int lr = lane & 15, lg = lane >> 4;
    const int n0 = blockIdx.x * 64 + w * 16;
    const int e0 = blockIdx.y * 64;
    const u16* wb = blockIdx.z ? wkb : wqb;
    u16* dst = blockIdx.z ? Kb : Qb;

    f32x4 acc[4];
#pragma unroll
    for (int cb = 0; cb < 4; ++cb) acc[cb] = f32x4{0.f, 0.f, 0.f, 0.f};

    for (int k0 = 0; k0 < 512; k0 += 32) {
        s16x8 a = *(const s16x8*)(xb + (n0 + lr) * 512 + k0 + lg * 8);
#pragma unroll
        for (int cb = 0; cb < 4; ++cb) {
            s16x8 b = *(const s16x8*)(wb + (e0 + cb * 16 + lr) * 512 + k0 + lg * 8);
            acc[cb] = __builtin_amdgcn_mfma_f32_16x16x32_bf16(a, b, acc[cb], 0, 0, 0);
        }
    }
#pragma unroll
    for (int cb = 0; cb < 4; ++cb)
#pragma unroll
        for (int r = 0; r < 4; ++r)
            dst[(n0 + lg * 4 + r) * 512 + e0 + cb * 16 + lr] = f2bf(acc[cb][r]);
}

// ---------- K2t: transpose Kb -> Kt[512][3072] (unchanged) ----------
__global__ __launch_bounds__(256) void k_transpose(const u16* __restrict__ Kb,
                                                   u16* __restrict__ Kt) {
    __shared__ u16 tile[64 * 68];
    const int t = threadIdx.x;
    const int n0 = blockIdx.x * 64, e0 = blockIdx.y * 64;
    const int tr = t >> 4, c4 = (t & 15) * 4;
#pragma unroll
    for (int p = 0; p < 4; ++p) {
        int row = p * 16 + tr;
        u16x4 v = *(const u16x4*)(Kb + (n0 + row) * 512 + e0 + c4);
        *(u16x4*)&tile[row * 68 + c4] = v;
    }
    __syncthreads();
#pragma unroll
    for (int p = 0; p < 4; ++p) {
        int er = p * 16 + tr;
        u16x4 v = { tile[(c4 + 0) * 68 + er], tile[(c4 + 1) * 68 + er],
                    tile[(c4 + 2) * 68 + er], tile[(c4 + 3) * 68 + er] };
        *(u16x4*)(Kt + (e0 + er) * 3072 + n0 + c4) = v;
    }
}

// ---------- K3: pass 1 — partial sumexp. 8 waves/block, wave = head. ----------
// grid (96 n-blocks of 32, 8 m-chunks of 384); 6 steps of 64 cols.
__global__ __launch_bounds__(512, 4) void k_pass1(
    const u16* __restrict__ Qb, const u16* __restrict__ Kb,
    const u64* __restrict__ adjp, float* __restrict__ sep)
{
    const int t = threadIdx.x, lane = t & 63, h = t >> 6;
    const int lr = lane & 15, lg = lane >> 4;
    const int n0 = blockIdx.x * 32;
    const int mbase = blockIdx.y * 384;

    s16x8 qa[2][2];
#pragma unroll
    for (int rb = 0; rb < 2; ++rb)
#pragma unroll
        for (int ks = 0; ks < 2; ++ks)
            qa[rb][ks] = *(const s16x8*)(Qb + (n0 + rb * 16 + lr) * 512 +
                                         h * 64 + ks * 32 + lg * 8);
    float racc[2][4];
#pragma unroll
    for (int rb = 0; rb < 2; ++rb)
#pragma unroll
        for (int r = 0; r < 4; ++r) racc[rb][r] = 0.f;

    for (int ms = 0; ms < 6; ++ms) {
        const int m0 = mbase + ms * 64;
        u64 aw[2][4];
#pragma unroll
        for (int rb = 0; rb < 2; ++rb)
#pragma unroll
            for (int r = 0; r < 4; ++r)
                aw[rb][r] = adjp[(n0 + rb * 16 + lg * 4 + r) * 48 + (m0 >> 6)];
        s16x8 b[4][2];
#pragma unroll
        for (int cb = 0; cb < 4; ++cb)
#pragma unroll
            for (int ks = 0; ks < 2; ++ks)
                b[cb][ks] = *(const s16x8*)(Kb + (m0 + cb * 16 + lr) * 512 +
                                            h * 64 + ks * 32 + lg * 8);
        f32x4 z = {0.f, 0.f, 0.f, 0.f};
#pragma unroll
        for (int rb = 0; rb < 2; ++rb)
#pragma unroll
            for (int cb = 0; cb < 4; ++cb) {
                f32x4 s = __builtin_amdgcn_mfma_f32_16x16x32_bf16(qa[rb][0], b[cb][0], z, 0, 0, 0);
                s = __builtin_amdgcn_mfma_f32_16x16x32_bf16(qa[rb][1], b[cb][1], s, 0, 0, 0);
#pragma unroll
                for (int r = 0; r < 4; ++r) {
                    float e = ((aw[rb][r] >> (cb * 16 + lr)) & 1ull)
                            ? exp2f(EXPSC * s[r]) : 0.f;
                    racc[rb][r] += e;
                }
            }
    }
#pragma unroll
    for (int rb = 0; rb < 2; ++rb)
#pragma unroll
        for (int r = 0; r < 4; ++r) {
            float v = racc[rb][r];
            v += __shfl_xor(v, 1); v += __shfl_xor(v, 2);
            v += __shfl_xor(v, 4); v += __shfl_xor(v, 8);
            if (lr == 0)
                sep[(blockIdx.y * 8 + h) * N_ + n0 + rb * 16 + lg * 4 + r] = v;
        }
}

// ---------- K4: finish — inv_se + energies (unchanged, proven) ----------
__global__ __launch_bounds__(64) void k_finish(
    const u16* __restrict__ Qb, const float* __restrict__ sep,
    float* __restrict__ inv_se, float* __restrict__ energies)
{
    const int lane = threadIdx.x;
    const int r = lane >> 3;
    const int h = lane & 7;
    const int n = blockIdx.x * 8 + r;

    float se = 0.f;
#pragma unroll
    for (int c = 0; c < 8; ++c) se += sep[(c * 8 + h) * N_ + n];

    float q2 = 0.f;
    const u16* qrow = Qb + n * 512 + h * 64;
#pragma unroll
    for (int j = 0; j < 8; ++j) {
        s16x8 v = *(const s16x8*)(qrow + j * 8);
#pragma unroll
        for (int e = 0; e < 8; ++e) {
            float f = b2f((u16)v[e]);
            q2 += f * f;
        }
    }

    inv_se[h * N_ + n] = 1.f / se;
    energies[h * N_ + n] = -8.0f * logf(se) + 0.5f * q2;
}

// ---------- K5: pass 2 — attn_mean + partial out. 8 waves/block, wave = head. ----------
// grid (96 n-blocks of 32, c2 chunks); m-tile 64 per step, 2 barriers per step.
__global__ __launch_bounds__(512, 4) void k_pass2(
    const u16* __restrict__ Qb, const u16* __restrict__ Kb,
    const u16* __restrict__ Kt, const float* __restrict__ inv_se,
    const u64* __restrict__ adjp, float* __restrict__ amean,
    float* __restrict__ pout, int mrange)
{
    __shared__ u16 Plds[8 * 32 * 72];   // [head][n 32][m 64 pad->72]
    const int t = threadIdx.x, lane = t & 63, h = t >> 6;
    const int lr = lane & 15, lg = lane >> 4;
    const int n0 = blockIdx.x * 32;
    const int mbase = blockIdx.y * mrange;

    s16x8 qa[2][2];
#pragma unroll
    for (int rb = 0; rb < 2; ++rb)
#pragma unroll
        for (int ks = 0; ks < 2; ++ks)
            qa[rb][ks] = *(const s16x8*)(Qb + (n0 + rb * 16 + lr) * 512 +
                                         h * 64 + ks * 32 + lg * 8);
    f32x4 invv[2];
#pragma unroll
    for (int rb = 0; rb < 2; ++rb)
        invv[rb] = *(const f32x4*)(inv_se + h * N_ + n0 + rb * 16 + lg * 4);

    f32x4 oacc[2][4];
#pragma unroll
    for (int rb = 0; rb < 2; ++rb)
#pragma unroll
        for (int db = 0; db < 4; ++db) oacc[rb][db] = f32x4{0.f, 0.f, 0.f, 0.f};

    const int msteps = mrange >> 6;
    for (int ms = 0; ms < msteps; ++ms) {
        const int m0 = mbase + ms * 64;
        u64 aw[2][4];
#pragma unroll
        for (int rb = 0; rb < 2; ++rb)
#pragma unroll
            for (int r = 0; r < 4; ++r)
                aw[rb][r] = adjp[(n0 + rb * 16 + lg * 4 + r) * 48 + (m0 >> 6)];
        // QK in two cb-pairs (register-pressure control)
        f32x4 z = {0.f, 0.f, 0.f, 0.f};
#pragma unroll
        for (int cp = 0; cp < 2; ++cp) {
            s16x8 b[2][2];
#pragma unroll
            for (int cc = 0; cc < 2; ++cc)
#pragma unroll
                for (int ks = 0; ks < 2; ++ks)
                    b[cc][ks] = *(const s16x8*)(Kb + (m0 + (cp * 2 + cc) * 16 + lr) * 512 +
                                                h * 64 + ks * 32 + lg * 8);
#pragma unroll
            for (int rb = 0; rb < 2; ++rb)
#pragma unroll
                for (int cc = 0; cc < 2; ++cc) {
                    const int cb = cp * 2 + cc;
                    f32x4 s = __builtin_amdgcn_mfma_f32_16x16x32_bf16(qa[rb][0], b[cc][0], z, 0, 0, 0);
                    s = __builtin_amdgcn_mfma_f32_16x16x32_bf16(qa[rb][1], b[cc][1], s, 0, 0, 0);
#pragma unroll
                    for (int r = 0; r < 4; ++r) {
                        float p = ((aw[rb][r] >> (cb * 16 + lr)) & 1ull)
                                ? exp2f(EXPSC * s[r]) * invv[rb][r] : 0.f;
                        Plds[(h * 32 + rb * 16 + lg * 4 + r) * 72 + cb * 16 + lr] = f2bf(p);
                    }
                }
        }
        __syncthreads();
        {   // attn_mean: thread -> (row = t>>4, 4 cols), summed over 8 heads
            const int row = t >> 4;
            const int c4 = (t & 15) * 4;
            f32x4 sum = {0.f, 0.f, 0.f, 0.f};
#pragma unroll
            for (int h2 = 0; h2 < 8; ++h2) {
                u16x4 pv = *(const u16x4*)&Plds[(h2 * 32 + row) * 72 + c4];
#pragma unroll
                for (int j = 0; j < 4; ++j) sum[j] += b2f(pv[j]);
            }
            f32x4 o;
#pragma unroll
            for (int j = 0; j < 4; ++j) o[j] = sum[j] * 0.125f;
            *(f32x4*)(amean + (size_t)(n0 + row) * 3072 + m0 + c4) = o;
        }
        // PV for own head
        {
            s16x8 pa[2][2];
#pragma unroll
            for (int rb = 0; rb < 2; ++rb)
#pragma unroll
                for (int ks = 0; ks < 2; ++ks)
                    pa[rb][ks] = *(const s16x8*)&Plds[(h * 32 + rb * 16 + lr) * 72 +
                                                      ks * 32 + lg * 8];
            s16x8 kb[4][2];
#pragma unroll
            for (int db = 0; db < 4; ++db)
#pragma unroll
                for (int ks = 0; ks < 2; ++ks)
                    kb[db][ks] = *(const s16x8*)(Kt + (h * 64 + db * 16 + lr) * 3072 +
                                                 m0 + ks * 32 + lg * 8);
#pragma unroll
            for (int rb = 0; rb < 2; ++rb)
#pragma unroll
                for (int db = 0; db < 4; ++db) {
                    oacc[rb][db] = __builtin_amdgcn_mfma_f32_16x16x32_bf16(
                        pa[rb][0], kb[db][0], oacc[rb][db], 0, 0, 0);
                    oacc[rb][db] = __builtin_amdgcn_mfma_f32_16x16x32_bf16(
                        pa[rb][1], kb[db][1], oacc[rb][db], 0, 0, 0);
                }
        }
        __syncthreads();
    }
    float* po = pout + (size_t)blockIdx.y * (N_ * E_);
#pragma unroll
    for (int rb = 0; rb < 2; ++rb)
#pragma unroll
        for (int db = 0; db < 4; ++db)
#pragma unroll
            for (int r = 0; r < 4; ++r)
                po[(n0 + rb * 16 + lg * 4 + r) * 512 +
                   h * 64 + db * 16 + lr] = oacc[rb][db][r];
}

// ---------- K6: reduce partial out (unchanged) ----------
__global__ void k_reduce(const float* __restrict__ pout, float* __restrict__ out, int c2) {
    int i = blockIdx.x * blockDim.x + threadIdx.x;
    if (i >= (N_ * E_) / 4) return;
    const f32x4* p4 = (const f32x4*)pout;
    f32x4 s = p4[i];
    for (int c = 1; c < c2; ++c) s += p4[c * ((N_ * E_) / 4) + i];
    ((f32x4*)out)[i] = s;
}

extern "C" void kernel_launch(void* const* d_in, const int* in_sizes, int n_in,
                              void* d_out, int out_size, void* d_ws, size_t ws_size,
                              hipStream_t stream) {
    const float* x  = (const float*)d_in[0];
    const int*  adj = (const int*)d_in[1];     // bool input arrives as int32
    const float* WQ = (const float*)d_in[2];
    const float* WK = (const float*)d_in[3];
    float* out      = (float*)d_out;
    float* amean    = out + (size_t)N_ * E_;
    float* energies = out + (size_t)N_ * E_ + (size_t)N_ * N_;

    char* ws = (char*)d_ws;
    u16* xb     = (u16*)(ws);                 // 3.1 MB, dead after k_proj
    u64* adjp   = (u64*)(ws);                 // 1.18 MB, written after k_proj
    u16* wqb    = (u16*)(ws + 3145728);
    u16* wkb    = (u16*)(ws + 3670016);
    u16* Qb     = (u16*)(ws + 4194304);
    u16* Kb     = (u16*)(ws + 7340032);
    u16* Kt     = (u16*)(ws + 10485760);
    float* sep  = (float*)(ws + 13729792);
    float* inv_se = (float*)(ws + 14516224);
    float* pout = (float*)(ws + 14614528);

    int c2 = 1;
    const int cands[5] = {6, 4, 3, 2, 1};
    for (int i = 0; i < 5; ++i) {
        if (14614528ull + (size_t)cands[i] * ((size_t)N_ * E_ * 4) <= ws_size) {
            c2 = cands[i];
            break;
        }
    }

    k_cvt<<<dim3(1536), dim3(256), 0, stream>>>(x, xb, (N_ * 512) / 4);
    k_cvt<<<dim3(256), dim3(256), 0, stream>>>(WQ, wqb, (512 * 512) / 4);
    k_cvt<<<dim3(256), dim3(256), 0, stream>>>(WK, wkb, (512 * 512) / 4);
    k_proj<<<dim3(48, 8, 2), dim3(256), 0, stream>>>(xb, wqb, wkb, Qb, Kb);
    k_transpose<<<dim3(48, 8), dim3(256), 0, stream>>>(Kb, Kt);
    // pack adj AFTER k_proj: adjp aliases the now-dead xb region
    k_adjpack<<<dim3((N_ * N_) / 256), dim3(256), 0, stream>>>(adj, adjp);
    k_pass1<<<dim3(96, 8), dim3(512), 0, stream>>>(Qb, Kb, adjp, sep);
    k_finish<<<dim3(384), dim3(64), 0, stream>>>(Qb, sep, inv_se, energies);
    k_pass2<<<dim3(96, c2), dim3(512), 0, stream>>>(Qb, Kb, Kt, inv_se, adjp, amean,
                                                    pout, N_ / c2);
    k_reduce<<<dim3(1536), dim3(256), 0, stream>>>(pout, out, c2);
}